// Round 7
// baseline (314.478 us; speedup 1.0000x reference)
//
#include <hip/hip_runtime.h>

#define B_ 8
#define NH 12
#define NTOK 1025
#define FT 768
#define MROWS (B_*NTOK)      // 8200
#define QPAD 1025            // Q token stride
#define CH2 34               // 32-token chunks
#define NQT 36               // 32-row Q tiles
#define NTT 34               // 32-token bias tiles
#define NDIST 3972
#define LOG2E 1.44269504089f

typedef __bf16 bf16x8 __attribute__((ext_vector_type(8)));
typedef __bf16 bf16x2 __attribute__((ext_vector_type(2)));
typedef float floatx4 __attribute__((ext_vector_type(4)));
typedef float floatx16 __attribute__((ext_vector_type(16)));
typedef int intx4 __attribute__((ext_vector_type(4)));

// async global->LDS, 16B/lane; LDS dst wave-uniform, HW scatters +lane*16.
__device__ __forceinline__ void async_ld16(const void* gp, void* lp) {
  __builtin_amdgcn_global_load_lds(
      (const __attribute__((address_space(1))) void*)gp,
      (__attribute__((address_space(3))) void*)lp, 16, 0, 0);
}

__global__ __launch_bounds__(256) void cvt_bf16(const float* __restrict__ src,
                                                __bf16* __restrict__ dst, int n4) {
  int i = blockIdx.x * 256 + threadIdx.x;
  if (i >= n4) return;
  float4 v = ((const float4*)src)[i];
  __bf16 o[4] = {(__bf16)v.x, (__bf16)v.y, (__bf16)v.z, (__bf16)v.w};
  *(uint2*)(dst + 4 * (size_t)i) = *(uint2*)o;
}

// table (NDIST, NH) fp32 -> tableT[h][dist] bf16, pre-scaled by log2(e).
__global__ __launch_bounds__(256) void table_prep(const float* __restrict__ table,
                                                  __bf16* __restrict__ tableT) {
  int i = blockIdx.x * 256 + threadIdx.x;
  if (i >= NH * NDIST) return;
  int h = i / NDIST, d = i - h * NDIST;
  tableT[i] = (__bf16)(table[(size_t)d * NH + h] * LOG2E);
}

// ---------------- relpos bias gather into 32x32 S^T C-fragment tiles ----------------
// Bb[h][qt][tt][lane*16+j]: bias[qrow=qt*32+(lane&31)][token=tt*32+(j&3)+8*(j>>2)+4*(lane>>5)]
// values pre-scaled by log2(e) (softmax uses exp2). pad tokens -> -1e30 mask.
__global__ __launch_bounds__(256) void bias_gather_t(
    const int* __restrict__ idx, const __bf16* __restrict__ tableT,
    __bf16* __restrict__ Bb) {
  __shared__ int ids_l[32][33];
  const int qt = blockIdx.x, tt = blockIdx.y;
  const int t = threadIdx.x;
  {
    const int row = t >> 3, c4 = (t & 7) * 4;
    int qrow = qt * 32 + row; if (qrow > NTOK - 1) qrow = NTOK - 1;
    const int* src = idx + (size_t)qrow * NTOK;
#pragma unroll
    for (int j = 0; j < 4; ++j) {
      int token = tt * 32 + c4 + j; if (token > NTOK - 1) token = NTOK - 1;
      ids_l[row][c4 + j] = src[token];
    }
  }
  __syncthreads();
  const int lane = t & 63, w = t >> 6;
  const int l31 = lane & 31, hb = lane >> 5;
  int ids[16]; bool ok[16];
#pragma unroll
  for (int j = 0; j < 16; ++j) {
    const int col = (j & 3) + 8 * (j >> 2) + 4 * hb;
    ok[j] = tt * 32 + col < NTOK;
    ids[j] = ids_l[l31][col];
  }
#pragma unroll
  for (int g = 0; g < 3; ++g) {
    const int h = w + g * 4;
    const __bf16* tb = tableT + (size_t)h * NDIST;
    __bf16 v[16] __attribute__((aligned(16)));
#pragma unroll
    for (int j = 0; j < 16; ++j)
      v[j] = ok[j] ? tb[ids[j]] : (__bf16)(-1e30f);
    uint4* dst = (uint4*)(Bb + (((size_t)h * NQT + qt) * NTT + tt) * 1024 + lane * 16);
    dst[0] = ((uint4*)v)[0];
    dst[1] = ((uint4*)v)[1];
  }
}

// ---------------- 256x128 GEMM core, 8 waves, NB=3 lookahead-1 ----------------
__device__ __forceinline__ void gemm256_pipe(
    const __bf16* __restrict__ A, const __bf16* __restrict__ W,
    int am0, int n0, __bf16* Lt, floatx4 acc[4][4]) {
  const int tid = threadIdx.x, wave = tid >> 6, lane = tid & 63;
  const int l = lane & 15, qd = lane >> 4;
  const int srow = lane >> 2, sg = lane & 3;
  const int swb = (sg ^ (srow & 3)) * 8;        // staging XOR swizzle (row&3 == srow&3)
  const int wr = wave >> 1, wc = wave & 1;

  const __bf16* gsrc[3];
  int gdst[3];
#pragma unroll
  for (int i = 0; i < 3; ++i) {
    const int g = wave * 3 + i;
    if (g < 16) {                               // A rows
      int row = am0 + g * 16 + srow; if (row > MROWS - 1) row = MROWS - 1;
      gsrc[i] = A + (size_t)row * FT + swb;
      gdst[i] = g * 512;
    } else {                                    // B rows
      const int row = n0 + (g - 16) * 16 + srow;
      gsrc[i] = W + (size_t)row * FT + swb;
      gdst[i] = 8192 + (g - 16) * 512;
    }
  }
  const int fsw = (qd ^ (l & 3)) * 8;           // fragment-read swizzle

  auto issue = [&](int k, int buf) {
    __bf16* base = Lt + buf * 12288;
#pragma unroll
    for (int i = 0; i < 3; ++i)
      async_ld16(gsrc[i] + k * 32, base + gdst[i]);
  };
  auto step = [&](int buf) {
    __builtin_amdgcn_s_barrier();
    const __bf16* ab = Lt + buf * 12288;
    const __bf16* bb = ab + 8192;
    bf16x8 aF[4], bF[4];
#pragma unroll
    for (int t = 0; t < 4; ++t)
      aF[t] = *(const bf16x8*)(ab + (wr * 64 + t * 16 + l) * 32 + fsw);
#pragma unroll
    for (int u = 0; u < 4; ++u)
      bF[u] = *(const bf16x8*)(bb + (wc * 64 + u * 16 + l) * 32 + fsw);
#pragma unroll
    for (int t = 0; t < 4; ++t)
#pragma unroll
      for (int u = 0; u < 4; ++u)
        acc[t][u] = __builtin_amdgcn_mfma_f32_16x16x32_bf16(aF[t], bF[u], acc[t][u], 0, 0, 0);
  };

  issue(0, 0);
  int b0 = 0;
  for (int k = 0; k < 24; ++k) {                // FT/32 = 24
    if (k < 23) {
      int b1 = b0 + 1; if (b1 == 3) b1 = 0;
      issue(k + 1, b1);
      __builtin_amdgcn_s_waitcnt(0x0F73);       // vmcnt(3): k landed, k+1 in flight
    } else {
      __builtin_amdgcn_s_waitcnt(0x0F70);       // vmcnt(0)
    }
    step(b0);
    ++b0; if (b0 == 3) b0 = 0;
  }
}

// ---------------- QKV projection GEMM + bias/scale epilogue (256x128) ----------------
// Bijective XCD-chunked swizzle (m204): nwg=594=8*74+2.
__global__ __launch_bounds__(512, 4) void qkv_gemm256(
    const __bf16* __restrict__ tokens, const __bf16* __restrict__ qkvw,
    const float* __restrict__ qbias, const float* __restrict__ vbias,
    __bf16* __restrict__ Qb, __bf16* __restrict__ Kc, __bf16* __restrict__ Vc) {
  __shared__ __bf16 Lt[3 * 12288];              // 72 KB
  const int u0 = blockIdx.x;
  const int c = u0 & 7, i0 = u0 >> 3;           // q=74, r=2
  const int base = (c < 2) ? c * 75 : 150 + (c - 2) * 74;
  const int w = base + i0;
  const int mt = w / 18, ni = w % 18;           // 33 x 18
  const int am0 = mt * 256, n0 = ni * 128;
  const int tid = threadIdx.x, wave = tid >> 6, lane = tid & 63;
  const int l = lane & 15, qd = lane >> 4;
  const int wr = wave >> 1, wc = wave & 1;
  floatx4 acc[4][4];
#pragma unroll
  for (int t = 0; t < 4; ++t)
#pragma unroll
    for (int u = 0; u < 4; ++u) acc[t][u] = (floatx4){0.f, 0.f, 0.f, 0.f};
  gemm256_pipe(tokens, qkvw, am0, n0, Lt, acc);

  const int which = ni / 6;                     // 0=Q 1=K 2=V (block-uniform)
  const int nrem0 = (ni - which * 6) * 128;
#pragma unroll
  for (int u = 0; u < 4; ++u) {
    const int rem = nrem0 + wc * 64 + u * 16 + l;
    const int h = rem >> 6, f = rem & 63;
    const float qb = (which == 0) ? qbias[h * 64 + f] : 0.f;
    const float vb = (which == 2) ? vbias[h * 64 + f] : 0.f;
#pragma unroll
    for (int t = 0; t < 4; ++t) {
      const int gmb = am0 + wr * 64 + t * 16 + qd * 4;
#pragma unroll
      for (int r = 0; r < 4; ++r) {
        const int gm = gmb + r;
        if (gm >= MROWS) continue;
        const int b = (int)(((unsigned)gm * 16369u) >> 24);
        const int tok = gm - b * 1025;
        const size_t bh = (size_t)(b * NH + h);
        const float v = acc[t][u][r];
        if (which == 0) {
          Qb[(bh * QPAD + tok) * 64 + f] = (__bf16)((v + qb) * (0.125f * LOG2E));
        } else if (which == 1) {
          // Kc 32-tok chunks: [bh][tok>>5][dg=f>>3][tok&31][f&7]
          const size_t e = (bh * CH2 + (tok >> 5)) * 2048 +
                           (f >> 3) * 256 + (tok & 31) * 8 + (f & 7);
          Kc[e] = (__bf16)v;
        } else {
          // Vc 32-tok chunks: [bh][tok>>5][tg=(tok>>3)&3][f][tok&7]
          const size_t e = (bh * CH2 + (tok >> 5)) * 2048 +
                           (((tok >> 3) & 3) * 64 + f) * 8 + (tok & 7);
          Vc[e] = (__bf16)(v + vb);
        }
      }
    }
  }
}

// ---------------- output projection GEMM + bias (fp32 out), 256x128 ----------------
// Bijective XCD-chunked swizzle: nwg=198=8*24+6.
__global__ __launch_bounds__(512, 4) void proj_gemm256(
    const __bf16* __restrict__ Ao, const __bf16* __restrict__ projw,
    const float* __restrict__ projb, float* __restrict__ out) {
  __shared__ __bf16 Lt[3 * 12288];
  const int u0 = blockIdx.x;
  const int c = u0 & 7, i0 = u0 >> 3;           // q=24, r=6
  const int base = (c < 6) ? c * 25 : 150 + (c - 6) * 24;
  const int w = base + i0;
  const int mt = w / 6, ni = w % 6;             // 33 x 6
  const int am0 = mt * 256, n0 = ni * 128;
  const int tid = threadIdx.x, wave = tid >> 6, lane = tid & 63;
  const int l = lane & 15, qd = lane >> 4;
  const int wr = wave >> 1, wc = wave & 1;
  floatx4 acc[4][4];
#pragma unroll
  for (int t = 0; t < 4; ++t)
#pragma unroll
    for (int u = 0; u < 4; ++u) acc[t][u] = (floatx4){0.f, 0.f, 0.f, 0.f};
  gemm256_pipe(Ao, projw, am0, n0, Lt, acc);

#pragma unroll
  for (int u = 0; u < 4; ++u) {
    const int gn = n0 + wc * 64 + u * 16 + l;
    const float pb = projb[gn];
#pragma unroll
    for (int t = 0; t < 4; ++t) {
      const int gmb = am0 + wr * 64 + t * 16 + qd * 4;
#pragma unroll
      for (int r = 0; r < 4; ++r) {
        const int gm = gmb + r;
        if (gm < MROWS) out[(size_t)gm * FT + gn] = acc[t][u][r] + pb;
      }
    }
  }
}

// ---------------- flash attention: 4 waves / block, 64-token chunks ----------------
// Wave owns one 32-row Q tile (qt = blockIdx.y*4 + wave); 4 waves share K/V staging
// (waves 0,1 stage K halves; 2,3 stage V halves; 4KB/wave/chunk). NB=3 rotating 16KB
// buffer sets (48KB LDS -> 3 blocks/CU), lookahead-2, steady vmcnt(8) = stage(c+1)4 +
// bias(c+1)4. Buf hazard: write (c+2)%3 after barrier(c); last read compute(c-1),
// done by all waves at barrier(c) -> safe. Bias is the MFMA C-init (st starts at
// bias, exp2 reads st directly). P^T exchange via verified xor-32 shuffle.
// Pad tokens: bias -1e30 -> exp2()==0 -> K/V garbage inert.
__global__ __launch_bounds__(256, 3) void attn_flash(
    const __bf16* __restrict__ Qb, const __bf16* __restrict__ Kc,
    const __bf16* __restrict__ Vc, const __bf16* __restrict__ Bb,
    __bf16* __restrict__ Ao) {
  __shared__ __bf16 Kl[3][4096], Vl[3][4096];   // 48 KB total
  const int bh = blockIdx.x;
  const int h = bh % NH, b = bh / NH;
  const int wave = threadIdx.x >> 6, lane = threadIdx.x & 63;
  const int l31 = lane & 31, hb = lane >> 5;
  const int qt = blockIdx.y * 4 + wave;
  int qrow = qt * 32 + l31; if (qrow > NTOK - 1) qrow = NTOK - 1;

  // Q fragments (B-operand): B[n=qrow=lane&31][k = dk*16 + hb*8 + i]
  bf16x8 qf[4];
  {
    const __bf16* Qp = Qb + ((size_t)bh * QPAD + qrow) * 64 + hb * 8;
#pragma unroll
    for (int d = 0; d < 4; ++d) qf[d] = *(const bf16x8*)(Qp + d * 16);
  }

  floatx16 o0, o1;
#pragma unroll
  for (int j = 0; j < 16; ++j) { o0[j] = 0.f; o1[j] = 0.f; }
  float lsA = 0.f, lsB = 0.f;

  // staging role: waves 0,1 -> K halves; waves 2,3 -> V halves (2KB x2 each)
  const int sw = wave & 1;
  const __bf16* Sg = ((wave < 2) ? Kc : Vc) + (size_t)bh * CH2 * 2048 +
                     sw * 2048 + lane * 8;
  __bf16* Sl0 = ((wave < 2) ? &Kl[0][0] : &Vl[0][0]) + sw * 2048;
  const __bf16* Bg = Bb + ((size_t)h * NQT + qt) * NTT * 1024 + lane * 16;

  auto issueS = [&](int c2, int buf) {
    const __bf16* src = Sg + (size_t)c2 * 4096;
    __bf16* dst = Sl0 + buf * 4096;
    async_ld16(src, dst);
    async_ld16(src + 512, dst + 512);
    async_ld16(src + 1024, dst + 1024);
    async_ld16(src + 1536, dst + 1536);
  };

  bf16x8 bA0, bA1, bA2, bA3, bB0, bB1, bB2, bB3;
  auto loadBA = [&](int c2) {
    const __bf16* p = Bg + (size_t)(2 * c2) * 1024;
    bA0 = *(const bf16x8*)(p);
    bA1 = *(const bf16x8*)(p + 8);
    bA2 = *(const bf16x8*)(p + 1024);
    bA3 = *(const bf16x8*)(p + 1032);
  };
  auto loadBB = [&](int c2) {
    const __bf16* p = Bg + (size_t)(2 * c2) * 1024;
    bB0 = *(const bf16x8*)(p);
    bB1 = *(const bf16x8*)(p + 8);
    bB2 = *(const bf16x8*)(p + 1024);
    bB3 = *(const bf16x8*)(p + 1032);
  };

  floatx16 st0, st1;
  auto qkPart = [&](int buf, bf16x8 c0, bf16x8 c1, bf16x8 c2, bf16x8 c3) {
    const __bf16* Kb = &Kl[buf][0];
    // C-init = bias (pre-scaled log2e; pad = -1e30)
#pragma unroll
    for (int j = 0; j < 16; ++j) {
      st0[j] = (float)(j < 8 ? c0[j] : c1[j - 8]);
      st1[j] = (float)(j < 8 ? c2[j] : c3[j - 8]);
    }
    __builtin_amdgcn_s_setprio(1);
#pragma unroll
    for (int dk = 0; dk < 4; ++dk) {
      bf16x8 a0 = *(const bf16x8*)(Kb + ((dk * 2 + hb) * 32 + l31) * 8);
      bf16x8 a1 = *(const bf16x8*)(Kb + 2048 + ((dk * 2 + hb) * 32 + l31) * 8);
      st0 = __builtin_amdgcn_mfma_f32_32x32x16_bf16(a0, qf[dk], st0, 0, 0, 0);
      st1 = __builtin_amdgcn_mfma_f32_32x32x16_bf16(a1, qf[dk], st1, 0, 0, 0);
    }
    __builtin_amdgcn_s_setprio(0);
  };

  auto svPart = [&](int buf) {
#pragma unroll
    for (int th = 0; th < 2; ++th) {
      const floatx16& st = th ? st1 : st0;
      const __bf16* Vb = &Vl[buf][0] + th * 2048;
      float e[16];
#pragma unroll
      for (int j = 0; j < 16; ++j) e[j] = __builtin_amdgcn_exp2f(st[j]);
      lsA += ((e[0] + e[1]) + (e[2] + e[3])) + ((e[4] + e[5]) + (e[6] + e[7]));
      lsB += ((e[8] + e[9]) + (e[10] + e[11])) + ((e[12] + e[13]) + (e[14] + e[15]));
      int pk[8];
#pragma unroll
      for (int j2 = 0; j2 < 8; ++j2) {
        bf16x2 pr = {(__bf16)e[2 * j2], (__bf16)e[2 * j2 + 1]};
        pk[j2] = __builtin_bit_cast(int, pr);
      }
      __builtin_amdgcn_s_setprio(1);
#pragma unroll
      for (int ks = 0; ks < 2; ++ks) {
        // verified xor-32 exchange (round-5): P^T B-fragments
        const int r01a = pk[4 * ks + 0], r01b = pk[4 * ks + 1];
        const int r23a = pk[4 * ks + 2], r23b = pk[4 * ks + 3];
        const int t01a = __shfl_xor(r01a, 32), t01b = __shfl_xor(r01b, 32);
        const int t23a = __shfl_xor(r23a, 32), t23b = __shfl_xor(r23b, 32);
        intx4 fi;
        fi[0] = hb ? t23a : r01a;
        fi[1] = hb ? t23b : r01b;
        fi[2] = hb ? r23a : t01a;
        fi[3] = hb ? r23b : t01b;
        bf16x8 pb = __builtin_bit_cast(bf16x8, fi);
        bf16x8 va0 = *(const bf16x8*)(Vb + ((ks * 2 + hb) * 64 + l31) * 8);
        bf16x8 va1 = *(const bf16x8*)(Vb + ((ks * 2 + hb) * 64 + 32 + l31) * 8);
        o0 = __builtin_amdgcn_mfma_f32_32x32x16_bf16(va0, pb, o0, 0, 0, 0);
        o1 = __builtin_amdgcn_mfma_f32_32x32x16_bf16(va1, pb, o1, 0, 0, 0);
      }
      __builtin_amdgcn_s_setprio(0);
    }
  };

  // prologue: queue [stage(0)4, biasA4, stage(1)4, biasB4] -> first wait vmcnt(8)
  issueS(0, 0);
  loadBA(0);
  issueS(1, 1);
  loadBB(1);
  int bufc = 0;
  for (int ci = 0; ci < 8; ++ci) {
    const int c = 2 * ci;
    // even chunk c (bias A)
    __builtin_amdgcn_s_waitcnt(0x0F78);          // vmcnt(8)
    __builtin_amdgcn_s_barrier();
    qkPart(bufc, bA0, bA1, bA2, bA3);
    { int pb_ = bufc + 2; if (pb_ >= 3) pb_ -= 3; issueS(c + 2, pb_); loadBA(c + 2); }
    svPart(bufc);
    bufc = (bufc + 1 == 3) ? 0 : bufc + 1;
    // odd chunk c+1 (bias B)
    __builtin_amdgcn_s_waitcnt(0x0F78);          // vmcnt(8)
    __builtin_amdgcn_s_barrier();
    qkPart(bufc, bB0, bB1, bB2, bB3);
    if (ci < 7) { int pb_ = bufc + 2; if (pb_ >= 3) pb_ -= 3; issueS(c + 3, pb_); loadBB(c + 3); }
    svPart(bufc);
    bufc = (bufc + 1 == 3) ? 0 : bufc + 1;
  }
  // tail chunk 16 (bias A loaded at c=14)
  __builtin_amdgcn_s_waitcnt(0x0F70);            // vmcnt(0)
  __builtin_amdgcn_s_barrier();
  qkPart(bufc, bA0, bA1, bA2, bA3);
  svPart(bufc);

  const float ls = lsA + lsB;
  const float ltot = ls + __shfl_xor(ls, 32);
  const float rinv = 1.0f / ltot;
  const int tok = qt * 32 + l31;
  if (tok < NTOK) {
    __bf16* op = Ao + ((size_t)b * NTOK + tok) * FT + h * 64;
#pragma unroll
    for (int ft = 0; ft < 2; ++ft) {
#pragma unroll
      for (int jg = 0; jg < 4; ++jg) {
        const int f = ft * 32 + jg * 8 + hb * 4;
        __bf16 v4[4] __attribute__((aligned(8)));
#pragma unroll
        for (int q = 0; q < 4; ++q) {
          const float ov = ft ? o1[jg * 4 + q] : o0[jg * 4 + q];
          v4[q] = (__bf16)(ov * rinv);
        }
        *(uint2*)(op + f) = *(uint2*)v4;
      }
    }
  }
}

extern "C" void kernel_launch(void* const* d_in, const int* in_sizes, int n_in,
                              void* d_out, int out_size, void* d_ws, size_t ws_size,
                              hipStream_t stream) {
  (void)in_sizes; (void)n_in; (void)out_size; (void)ws_size;
  const float* tokens = (const float*)d_in[0];
  const float* qkvw   = (const float*)d_in[1];
  const float* qbias  = (const float*)d_in[2];
  const float* vbias  = (const float*)d_in[3];
  const float* table  = (const float*)d_in[4];
  const float* projw  = (const float*)d_in[5];
  const float* projb  = (const float*)d_in[6];
  const int*   rpidx  = (const int*)d_in[7];
  float* out = (float*)d_out;
  char* ws = (char*)d_ws;

  const size_t QBQ = (size_t)B_ * NH * QPAD * 64 * 2;          // 12,595,200 B
  const size_t KVB = (size_t)B_ * NH * CH2 * 2048 * 2;         // 13,369,344 B
  const size_t BBT = (size_t)NH * NQT * NTT * 1024 * 2;        // 30,081,024 B
  const size_t AOB = (size_t)MROWS * FT * 2;                   // 12,595,200 B
  const size_t WQB = (size_t)3 * FT * FT * 2;
  const size_t WPB = (size_t)FT * FT * 2;
  __bf16* Qb = (__bf16*)(ws);
  __bf16* Kc = (__bf16*)(ws + QBQ);
  __bf16* Vc = (__bf16*)(ws + QBQ + KVB);
  __bf16* Bb = (__bf16*)(ws + QBQ + 2 * KVB);
  __bf16* Tb = (__bf16*)(ws + QBQ + 2 * KVB + BBT);  // tokens bf16; Ao aliases (dead after qkv)
  __bf16* Ao = Tb;
  __bf16* Wq = (__bf16*)(ws + QBQ + 2 * KVB + BBT + AOB);
  __bf16* Wp = (__bf16*)(ws + QBQ + 2 * KVB + BBT + AOB + WQB);
  __bf16* Tt = (__bf16*)(ws + QBQ + 2 * KVB + BBT + AOB + WQB + WPB);
  // total ~86.8 MB

  cvt_bf16<<<(MROWS * FT / 4 + 255) / 256, 256, 0, stream>>>(tokens, Tb, MROWS * FT / 4);
  cvt_bf16<<<(3 * FT * FT / 4 + 255) / 256, 256, 0, stream>>>(qkvw, Wq, 3 * FT * FT / 4);
  cvt_bf16<<<(FT * FT / 4 + 255) / 256, 256, 0, stream>>>(projw, Wp, FT * FT / 4);
  table_prep<<<(NH * NDIST + 255) / 256, 256, 0, stream>>>(table, Tt);
  bias_gather_t<<<dim3(NQT, NTT), 256, 0, stream>>>(rpidx, Tt, Bb);
  qkv_gemm256<<<33 * 18, 512, 0, stream>>>(Tb, Wq, qbias, vbias, Qb, Kc, Vc);
  attn_flash<<<dim3(B_ * NH, 9), 256, 0, stream>>>(Qb, Kc, Vc, Bb, Ao);
  proj_gemm256<<<33 * 6, 512, 0, stream>>>(Ao, Wp, projb, out);
}

// Round 8
// 247.441 us; speedup vs baseline: 1.2709x; 1.2709x over previous
//
#include <hip/hip_runtime.h>

#define B_ 8
#define NH 12
#define NTOK 1025
#define FT 768
#define MROWS (B_*NTOK)      // 8200
#define QPAD 1025            // Q token stride
#define CH2 34               // 32-token chunks
#define NQT 36               // 32-row Q tiles
#define NTT 34               // 32-token bias tiles
#define NDIST 3972
#define LOG2E 1.44269504089f

typedef __bf16 bf16x8 __attribute__((ext_vector_type(8)));
typedef __bf16 bf16x2 __attribute__((ext_vector_type(2)));
typedef float floatx4 __attribute__((ext_vector_type(4)));
typedef float floatx16 __attribute__((ext_vector_type(16)));
typedef int intx4 __attribute__((ext_vector_type(4)));

// async global->LDS, 16B/lane; LDS dst wave-uniform, HW scatters +lane*16.
__device__ __forceinline__ void async_ld16(const void* gp, void* lp) {
  __builtin_amdgcn_global_load_lds(
      (const __attribute__((address_space(1))) void*)gp,
      (__attribute__((address_space(3))) void*)lp, 16, 0, 0);
}

__global__ __launch_bounds__(256) void cvt_bf16(const float* __restrict__ src,
                                                __bf16* __restrict__ dst, int n4) {
  int i = blockIdx.x * 256 + threadIdx.x;
  if (i >= n4) return;
  float4 v = ((const float4*)src)[i];
  __bf16 o[4] = {(__bf16)v.x, (__bf16)v.y, (__bf16)v.z, (__bf16)v.w};
  *(uint2*)(dst + 4 * (size_t)i) = *(uint2*)o;
}

// table (NDIST, NH) fp32 -> tableT[h][dist] bf16, pre-scaled by log2(e).
__global__ __launch_bounds__(256) void table_prep(const float* __restrict__ table,
                                                  __bf16* __restrict__ tableT) {
  int i = blockIdx.x * 256 + threadIdx.x;
  if (i >= NH * NDIST) return;
  int h = i / NDIST, d = i - h * NDIST;
  tableT[i] = (__bf16)(table[(size_t)d * NH + h] * LOG2E);
}

// ---------------- relpos bias gather into 32x32 S^T C-fragment tiles ----------------
// Bb[h][qt][tt][lane*16+j]: bias[qrow=qt*32+(lane&31)][token=tt*32+(j&3)+8*(j>>2)+4*(lane>>5)]
// values pre-scaled by log2(e) (softmax uses exp2). pad tokens -> -1e30 mask.
__global__ __launch_bounds__(256) void bias_gather_t(
    const int* __restrict__ idx, const __bf16* __restrict__ tableT,
    __bf16* __restrict__ Bb) {
  __shared__ int ids_l[32][33];
  const int qt = blockIdx.x, tt = blockIdx.y;
  const int t = threadIdx.x;
  {
    const int row = t >> 3, c4 = (t & 7) * 4;
    int qrow = qt * 32 + row; if (qrow > NTOK - 1) qrow = NTOK - 1;
    const int* src = idx + (size_t)qrow * NTOK;
#pragma unroll
    for (int j = 0; j < 4; ++j) {
      int token = tt * 32 + c4 + j; if (token > NTOK - 1) token = NTOK - 1;
      ids_l[row][c4 + j] = src[token];
    }
  }
  __syncthreads();
  const int lane = t & 63, w = t >> 6;
  const int l31 = lane & 31, hb = lane >> 5;
  int ids[16]; bool ok[16];
#pragma unroll
  for (int j = 0; j < 16; ++j) {
    const int col = (j & 3) + 8 * (j >> 2) + 4 * hb;
    ok[j] = tt * 32 + col < NTOK;
    ids[j] = ids_l[l31][col];
  }
#pragma unroll
  for (int g = 0; g < 3; ++g) {
    const int h = w + g * 4;
    const __bf16* tb = tableT + (size_t)h * NDIST;
    __bf16 v[16] __attribute__((aligned(16)));
#pragma unroll
    for (int j = 0; j < 16; ++j)
      v[j] = ok[j] ? tb[ids[j]] : (__bf16)(-1e30f);
    uint4* dst = (uint4*)(Bb + (((size_t)h * NQT + qt) * NTT + tt) * 1024 + lane * 16);
    dst[0] = ((uint4*)v)[0];
    dst[1] = ((uint4*)v)[1];
  }
}

// ---------------- 256x128 GEMM core, 8 waves, NB=3 lookahead-1 ----------------
__device__ __forceinline__ void gemm256_pipe(
    const __bf16* __restrict__ A, const __bf16* __restrict__ W,
    int am0, int n0, __bf16* Lt, floatx4 acc[4][4]) {
  const int tid = threadIdx.x, wave = tid >> 6, lane = tid & 63;
  const int l = lane & 15, qd = lane >> 4;
  const int srow = lane >> 2, sg = lane & 3;
  const int swb = (sg ^ (srow & 3)) * 8;        // staging XOR swizzle (row&3 == srow&3)
  const int wr = wave >> 1, wc = wave & 1;

  const __bf16* gsrc[3];
  int gdst[3];
#pragma unroll
  for (int i = 0; i < 3; ++i) {
    const int g = wave * 3 + i;
    if (g < 16) {                               // A rows
      int row = am0 + g * 16 + srow; if (row > MROWS - 1) row = MROWS - 1;
      gsrc[i] = A + (size_t)row * FT + swb;
      gdst[i] = g * 512;
    } else {                                    // B rows
      const int row = n0 + (g - 16) * 16 + srow;
      gsrc[i] = W + (size_t)row * FT + swb;
      gdst[i] = 8192 + (g - 16) * 512;
    }
  }
  const int fsw = (qd ^ (l & 3)) * 8;           // fragment-read swizzle

  auto issue = [&](int k, int buf) {
    __bf16* base = Lt + buf * 12288;
#pragma unroll
    for (int i = 0; i < 3; ++i)
      async_ld16(gsrc[i] + k * 32, base + gdst[i]);
  };
  auto step = [&](int buf) {
    __builtin_amdgcn_s_barrier();
    const __bf16* ab = Lt + buf * 12288;
    const __bf16* bb = ab + 8192;
    bf16x8 aF[4], bF[4];
#pragma unroll
    for (int t = 0; t < 4; ++t)
      aF[t] = *(const bf16x8*)(ab + (wr * 64 + t * 16 + l) * 32 + fsw);
#pragma unroll
    for (int u = 0; u < 4; ++u)
      bF[u] = *(const bf16x8*)(bb + (wc * 64 + u * 16 + l) * 32 + fsw);
#pragma unroll
    for (int t = 0; t < 4; ++t)
#pragma unroll
      for (int u = 0; u < 4; ++u)
        acc[t][u] = __builtin_amdgcn_mfma_f32_16x16x32_bf16(aF[t], bF[u], acc[t][u], 0, 0, 0);
  };

  issue(0, 0);
  int b0 = 0;
  for (int k = 0; k < 24; ++k) {                // FT/32 = 24
    if (k < 23) {
      int b1 = b0 + 1; if (b1 == 3) b1 = 0;
      issue(k + 1, b1);
      __builtin_amdgcn_s_waitcnt(0x0F73);       // vmcnt(3): k landed, k+1 in flight
    } else {
      __builtin_amdgcn_s_waitcnt(0x0F70);       // vmcnt(0)
    }
    step(b0);
    ++b0; if (b0 == 3) b0 = 0;
  }
}

// ---------------- QKV projection GEMM + bias/scale epilogue (256x128) ----------------
// Bijective XCD-chunked swizzle (m204): nwg=594=8*74+2.
__global__ __launch_bounds__(512, 4) void qkv_gemm256(
    const __bf16* __restrict__ tokens, const __bf16* __restrict__ qkvw,
    const float* __restrict__ qbias, const float* __restrict__ vbias,
    __bf16* __restrict__ Qb, __bf16* __restrict__ Kc, __bf16* __restrict__ Vc) {
  __shared__ __bf16 Lt[3 * 12288];              // 72 KB
  const int u0 = blockIdx.x;
  const int c = u0 & 7, i0 = u0 >> 3;           // q=74, r=2
  const int base = (c < 2) ? c * 75 : 150 + (c - 2) * 74;
  const int w = base + i0;
  const int mt = w / 18, ni = w % 18;           // 33 x 18
  const int am0 = mt * 256, n0 = ni * 128;
  const int tid = threadIdx.x, wave = tid >> 6, lane = tid & 63;
  const int l = lane & 15, qd = lane >> 4;
  const int wr = wave >> 1, wc = wave & 1;
  floatx4 acc[4][4];
#pragma unroll
  for (int t = 0; t < 4; ++t)
#pragma unroll
    for (int u = 0; u < 4; ++u) acc[t][u] = (floatx4){0.f, 0.f, 0.f, 0.f};
  gemm256_pipe(tokens, qkvw, am0, n0, Lt, acc);

  const int which = ni / 6;                     // 0=Q 1=K 2=V (block-uniform)
  const int nrem0 = (ni - which * 6) * 128;
#pragma unroll
  for (int u = 0; u < 4; ++u) {
    const int rem = nrem0 + wc * 64 + u * 16 + l;
    const int h = rem >> 6, f = rem & 63;
    const float qb = (which == 0) ? qbias[h * 64 + f] : 0.f;
    const float vb = (which == 2) ? vbias[h * 64 + f] : 0.f;
#pragma unroll
    for (int t = 0; t < 4; ++t) {
      const int gmb = am0 + wr * 64 + t * 16 + qd * 4;
#pragma unroll
      for (int r = 0; r < 4; ++r) {
        const int gm = gmb + r;
        if (gm >= MROWS) continue;
        const int b = (int)(((unsigned)gm * 16369u) >> 24);
        const int tok = gm - b * 1025;
        const size_t bh = (size_t)(b * NH + h);
        const float v = acc[t][u][r];
        if (which == 0) {
          Qb[(bh * QPAD + tok) * 64 + f] = (__bf16)((v + qb) * (0.125f * LOG2E));
        } else if (which == 1) {
          // Kc 32-tok chunks: [bh][tok>>5][dg=f>>3][tok&31][f&7]
          const size_t e = (bh * CH2 + (tok >> 5)) * 2048 +
                           (f >> 3) * 256 + (tok & 31) * 8 + (f & 7);
          Kc[e] = (__bf16)v;
        } else {
          // Vc 32-tok chunks: [bh][tok>>5][tg=(tok>>3)&3][f][tok&7]
          const size_t e = (bh * CH2 + (tok >> 5)) * 2048 +
                           (((tok >> 3) & 3) * 64 + f) * 8 + (tok & 7);
          Vc[e] = (__bf16)(v + vb);
        }
      }
    }
  }
}

// ---------------- output projection GEMM + bias (fp32 out), 256x128 ----------------
// Bijective XCD-chunked swizzle: nwg=198=8*24+6.
__global__ __launch_bounds__(512, 4) void proj_gemm256(
    const __bf16* __restrict__ Ao, const __bf16* __restrict__ projw,
    const float* __restrict__ projb, float* __restrict__ out) {
  __shared__ __bf16 Lt[3 * 12288];
  const int u0 = blockIdx.x;
  const int c = u0 & 7, i0 = u0 >> 3;           // q=24, r=6
  const int base = (c < 6) ? c * 25 : 150 + (c - 6) * 24;
  const int w = base + i0;
  const int mt = w / 6, ni = w % 6;             // 33 x 6
  const int am0 = mt * 256, n0 = ni * 128;
  const int tid = threadIdx.x, wave = tid >> 6, lane = tid & 63;
  const int l = lane & 15, qd = lane >> 4;
  const int wr = wave >> 1, wc = wave & 1;
  floatx4 acc[4][4];
#pragma unroll
  for (int t = 0; t < 4; ++t)
#pragma unroll
    for (int u = 0; u < 4; ++u) acc[t][u] = (floatx4){0.f, 0.f, 0.f, 0.f};
  gemm256_pipe(Ao, projw, am0, n0, Lt, acc);

#pragma unroll
  for (int u = 0; u < 4; ++u) {
    const int gn = n0 + wc * 64 + u * 16 + l;
    const float pb = projb[gn];
#pragma unroll
    for (int t = 0; t < 4; ++t) {
      const int gmb = am0 + wr * 64 + t * 16 + qd * 4;
#pragma unroll
      for (int r = 0; r < 4; ++r) {
        const int gm = gmb + r;
        if (gm < MROWS) out[(size_t)gm * FT + gn] = acc[t][u][r] + pb;
      }
    }
  }
}

// ---------------- flash attention: 4 waves / block, 64-token chunks, low-reg ----------------
// Wave owns one 32-row Q tile; waves 0,1 stage K halves, 2,3 stage V halves (4KB each).
// NB=3 rotating 16KB sets (48KB LDS), lookahead-2. Halves INTERLEAVED per chunk
// (qk0,sv0,qk1,sv1) so only ONE floatx16 st is live (cuts 16 VGPRs vs round-7; the
// round-7 spill was 157MB of scratch writes). Issue order per chunk: stage(c+2) after
// qk0, bias(c+2) after qk1 -> at each chunk's wait exactly 8 newer loads outstanding
// -> steady vmcnt(8); tail vmcnt(0) at chunk 16. Buf hazard: write (c+2)%3 after
// barrier(c); last read was chunk c-1, sealed by barrier(c) -> safe.
// Bias is the MFMA C-init (pre-scaled log2e; pad -1e30 -> exp2()==0 -> K/V pad inert).
// P^T exchange via hardware-verified xor-32 shuffle.
__global__ __launch_bounds__(256) void attn_flash(
    const __bf16* __restrict__ Qb, const __bf16* __restrict__ Kc,
    const __bf16* __restrict__ Vc, const __bf16* __restrict__ Bb,
    __bf16* __restrict__ Ao) {
  __shared__ __bf16 Kl[3][4096], Vl[3][4096];   // 48 KB total
  const int bh = blockIdx.x;
  const int h = bh % NH, b = bh / NH;
  const int wave = threadIdx.x >> 6, lane = threadIdx.x & 63;
  const int l31 = lane & 31, hb = lane >> 5;
  const int qt = blockIdx.y * 4 + wave;
  int qrow = qt * 32 + l31; if (qrow > NTOK - 1) qrow = NTOK - 1;

  // Q fragments (B-operand): B[n=qrow=lane&31][k = dk*16 + hb*8 + i]
  bf16x8 qf[4];
  {
    const __bf16* Qp = Qb + ((size_t)bh * QPAD + qrow) * 64 + hb * 8;
#pragma unroll
    for (int d = 0; d < 4; ++d) qf[d] = *(const bf16x8*)(Qp + d * 16);
  }

  floatx16 o0, o1;
#pragma unroll
  for (int j = 0; j < 16; ++j) { o0[j] = 0.f; o1[j] = 0.f; }
  float lsA = 0.f, lsB = 0.f;

  // staging role: waves 0,1 -> K halves; waves 2,3 -> V halves (2KB x2 each)
  const int sw = wave & 1;
  const __bf16* Sg = ((wave < 2) ? Kc : Vc) + (size_t)bh * CH2 * 2048 +
                     sw * 2048 + lane * 8;
  __bf16* Sl0 = ((wave < 2) ? &Kl[0][0] : &Vl[0][0]) + sw * 2048;
  const __bf16* Bg = Bb + ((size_t)h * NQT + qt) * NTT * 1024 + lane * 16;

  auto issueS = [&](int c2, int buf) {
    const __bf16* src = Sg + (size_t)c2 * 4096;
    __bf16* dst = Sl0 + buf * 4096;
    async_ld16(src, dst);
    async_ld16(src + 512, dst + 512);
    async_ld16(src + 1024, dst + 1024);
    async_ld16(src + 1536, dst + 1536);
  };

  bf16x8 bA0, bA1, bA2, bA3, bB0, bB1, bB2, bB3;
  auto loadBA = [&](int c2) {
    const __bf16* p = Bg + (size_t)(2 * c2) * 1024;
    bA0 = *(const bf16x8*)(p);
    bA1 = *(const bf16x8*)(p + 8);
    bA2 = *(const bf16x8*)(p + 1024);
    bA3 = *(const bf16x8*)(p + 1032);
  };
  auto loadBB = [&](int c2) {
    const __bf16* p = Bg + (size_t)(2 * c2) * 1024;
    bB0 = *(const bf16x8*)(p);
    bB1 = *(const bf16x8*)(p + 8);
    bB2 = *(const bf16x8*)(p + 1024);
    bB3 = *(const bf16x8*)(p + 1032);
  };

  floatx16 st;                                   // single live S^T state
  auto qkHalf = [&](int buf, int th, bf16x8 c0, bf16x8 c1) {
    const __bf16* Kb = &Kl[buf][0] + th * 2048;
    // C-init = bias (pre-scaled log2e; pad = -1e30)
#pragma unroll
    for (int j = 0; j < 16; ++j) st[j] = (float)(j < 8 ? c0[j] : c1[j - 8]);
    __builtin_amdgcn_s_setprio(1);
#pragma unroll
    for (int dk = 0; dk < 4; ++dk) {
      bf16x8 a = *(const bf16x8*)(Kb + ((dk * 2 + hb) * 32 + l31) * 8);
      st = __builtin_amdgcn_mfma_f32_32x32x16_bf16(a, qf[dk], st, 0, 0, 0);
    }
    __builtin_amdgcn_s_setprio(0);
  };

  auto svHalf = [&](int buf, int th) {
    const __bf16* Vb = &Vl[buf][0] + th * 2048;
    float e[16];
#pragma unroll
    for (int j = 0; j < 16; ++j) e[j] = __builtin_amdgcn_exp2f(st[j]);
    lsA += ((e[0] + e[1]) + (e[2] + e[3])) + ((e[4] + e[5]) + (e[6] + e[7]));
    lsB += ((e[8] + e[9]) + (e[10] + e[11])) + ((e[12] + e[13]) + (e[14] + e[15]));
    int pk[8];
#pragma unroll
    for (int j2 = 0; j2 < 8; ++j2) {
      bf16x2 pr = {(__bf16)e[2 * j2], (__bf16)e[2 * j2 + 1]};
      pk[j2] = __builtin_bit_cast(int, pr);
    }
    __builtin_amdgcn_s_setprio(1);
#pragma unroll
    for (int ks = 0; ks < 2; ++ks) {
      // verified xor-32 exchange: P^T B-fragments
      const int r01a = pk[4 * ks + 0], r01b = pk[4 * ks + 1];
      const int r23a = pk[4 * ks + 2], r23b = pk[4 * ks + 3];
      const int t01a = __shfl_xor(r01a, 32), t01b = __shfl_xor(r01b, 32);
      const int t23a = __shfl_xor(r23a, 32), t23b = __shfl_xor(r23b, 32);
      intx4 fi;
      fi[0] = hb ? t23a : r01a;
      fi[1] = hb ? t23b : r01b;
      fi[2] = hb ? r23a : t01a;
      fi[3] = hb ? r23b : t01b;
      bf16x8 pb = __builtin_bit_cast(bf16x8, fi);
      bf16x8 va0 = *(const bf16x8*)(Vb + ((ks * 2 + hb) * 64 + l31) * 8);
      bf16x8 va1 = *(const bf16x8*)(Vb + ((ks * 2 + hb) * 64 + 32 + l31) * 8);
      o0 = __builtin_amdgcn_mfma_f32_32x32x16_bf16(va0, pb, o0, 0, 0, 0);
      o1 = __builtin_amdgcn_mfma_f32_32x32x16_bf16(va1, pb, o1, 0, 0, 0);
    }
    __builtin_amdgcn_s_setprio(0);
  };

  // prologue: queue [stage(0)4, biasA(0)4, stage(1)4, biasB(1)4]
  issueS(0, 0);
  loadBA(0);
  issueS(1, 1);
  loadBB(1);
  int bufc = 0;
  for (int ci = 0; ci < 8; ++ci) {
    const int c = 2 * ci;
    // even chunk c (bias A)
    __builtin_amdgcn_s_waitcnt(0x0F78);          // vmcnt(8): stage(c)+biasA(c) landed
    __builtin_amdgcn_s_barrier();
    qkHalf(bufc, 0, bA0, bA1);
    { int pb_ = bufc + 2; if (pb_ >= 3) pb_ -= 3; issueS(c + 2, pb_); }
    svHalf(bufc, 0);
    qkHalf(bufc, 1, bA2, bA3);
    loadBA(c + 2);
    svHalf(bufc, 1);
    bufc = (bufc + 1 == 3) ? 0 : bufc + 1;
    // odd chunk c+1 (bias B)
    __builtin_amdgcn_s_waitcnt(0x0F78);          // vmcnt(8)
    __builtin_amdgcn_s_barrier();
    qkHalf(bufc, 0, bB0, bB1);
    if (ci < 7) { int pb_ = bufc + 2; if (pb_ >= 3) pb_ -= 3; issueS(c + 3, pb_); }
    svHalf(bufc, 0);
    qkHalf(bufc, 1, bB2, bB3);
    if (ci < 7) loadBB(c + 3);
    svHalf(bufc, 1);
    bufc = (bufc + 1 == 3) ? 0 : bufc + 1;
  }
  // tail chunk 16 (stage+biasA issued at chunk 14)
  __builtin_amdgcn_s_waitcnt(0x0F70);            // vmcnt(0)
  __builtin_amdgcn_s_barrier();
  qkHalf(bufc, 0, bA0, bA1);
  svHalf(bufc, 0);
  qkHalf(bufc, 1, bA2, bA3);
  svHalf(bufc, 1);

  const float ls = lsA + lsB;
  const float ltot = ls + __shfl_xor(ls, 32);
  const float rinv = 1.0f / ltot;
  const int tok = qt * 32 + l31;
  if (tok < NTOK) {
    __bf16* op = Ao + ((size_t)b * NTOK + tok) * FT + h * 64;
#pragma unroll
    for (int ft = 0; ft < 2; ++ft) {
#pragma unroll
      for (int jg = 0; jg < 4; ++jg) {
        const int f = ft * 32 + jg * 8 + hb * 4;
        __bf16 v4[4] __attribute__((aligned(8)));
#pragma unroll
        for (int q = 0; q < 4; ++q) {
          const float ov = ft ? o1[jg * 4 + q] : o0[jg * 4 + q];
          v4[q] = (__bf16)(ov * rinv);
        }
        *(uint2*)(op + f) = *(uint2*)v4;
      }
    }
  }
}

extern "C" void kernel_launch(void* const* d_in, const int* in_sizes, int n_in,
                              void* d_out, int out_size, void* d_ws, size_t ws_size,
                              hipStream_t stream) {
  (void)in_sizes; (void)n_in; (void)out_size; (void)ws_size;
  const float* tokens = (const float*)d_in[0];
  const float* qkvw   = (const float*)d_in[1];
  const float* qbias  = (const float*)d_in[2];
  const float* vbias  = (const float*)d_in[3];
  const float* table  = (const float*)d_in[4];
  const float* projw  = (const float*)d_in[5];
  const float* projb  = (const float*)d_in[6];
  const int*   rpidx  = (const int*)d_in[7];
  float* out = (float*)d_out;
  char* ws = (char*)d_ws;

  const size_t QBQ = (size_t)B_ * NH * QPAD * 64 * 2;          // 12,595,200 B
  const size_t KVB = (size_t)B_ * NH * CH2 * 2048 * 2;         // 13,369,344 B
  const size_t BBT = (size_t)NH * NQT * NTT * 1024 * 2;        // 30,081,024 B
  const size_t AOB = (size_t)MROWS * FT * 2;                   // 12,595,200 B
  const size_t WQB = (size_t)3 * FT * FT * 2;
  const size_t WPB = (size_t)FT * FT * 2;
  __bf16* Qb = (__bf16*)(ws);
  __bf16* Kc = (__bf16*)(ws + QBQ);
  __bf16* Vc = (__bf16*)(ws + QBQ + KVB);
  __bf16* Bb = (__bf16*)(ws + QBQ + 2 * KVB);
  __bf16* Tb = (__bf16*)(ws + QBQ + 2 * KVB + BBT);  // tokens bf16; Ao aliases (dead after qkv)
  __bf16* Ao = Tb;
  __bf16* Wq = (__bf16*)(ws + QBQ + 2 * KVB + BBT + AOB);
  __bf16* Wp = (__bf16*)(ws + QBQ + 2 * KVB + BBT + AOB + WQB);
  __bf16* Tt = (__bf16*)(ws + QBQ + 2 * KVB + BBT + AOB + WQB + WPB);
  // total ~86.8 MB

  cvt_bf16<<<(MROWS * FT / 4 + 255) / 256, 256, 0, stream>>>(tokens, Tb, MROWS * FT / 4);
  cvt_bf16<<<(3 * FT * FT / 4 + 255) / 256, 256, 0, stream>>>(qkvw, Wq, 3 * FT * FT / 4);
  cvt_bf16<<<(FT * FT / 4 + 255) / 256, 256, 0, stream>>>(projw, Wp, FT * FT / 4);
  table_prep<<<(NH * NDIST + 255) / 256, 256, 0, stream>>>(table, Tt);
  bias_gather_t<<<dim3(NQT, NTT), 256, 0, stream>>>(rpidx, Tt, Bb);
  qkv_gemm256<<<33 * 18, 512, 0, stream>>>(Tb, Wq, qbias, vbias, Qb, Kc, Vc);
  attn_flash<<<dim3(B_ * NH, 9), 256, 0, stream>>>(Qb, Kc, Vc, Bb, Ao);
  proj_gemm256<<<33 * 6, 512, 0, stream>>>(Ao, Wp, projb, out);
}